// Round 3
// baseline (222.954 us; speedup 1.0000x reference)
//
#include <hip/hip_runtime.h>
#include <hip/hip_bf16.h>
#include <hip/hip_cooperative_groups.h>

namespace cg = cooperative_groups;

// LinearAttention_MLP on MI355X — round 8: fuse main_gemm + rmsnorm (cooperative).
// Math: k-softmax over size-1 axis == 1 -> s = 0.125 exactly -> out = 0.125*v.
// Fold: y = x @ Weff^T, Weff = 0.125*Wo@Wv (1024x1024).
// Pipeline (2 launches):
//   prep       : [blocks 0..255]   Weff = bf16(0.125*Wo@Wv)
//                [blocks 256..2303] Xbf = bf16(X)  (grid-stride, overlapped)
//   main_fused : COOPERATIVE, 256 blocks x 512 thr (1 block/CU, co-resident).
//                K-loop identical to round 7 (256x256 8-phase, counted vmcnt(6),
//                setprio). Epilogue: keep tile in regs; per-row partial sum-of-
//                squares (shfl-xor + LDS across waves) -> partial[row][4] (ws,
//                written-once, no atomics) -> grid.sync() -> sc = 32/max(||y||,eps)
//                -> out = acc*sc*g written fp32 straight from registers.
//                y_bf intermediate ELIMINATED (no 36MB write + 32MB re-read).
//
// Swizzle convention (validated, 0 bank conflicts):
//   STORE: LDS chunk c holds GLOBAL chunk c ^ (r&7)  (swizzle the global k only)
//   READ : global chunk q lives in LDS chunk q ^ (r&7)
//
// WORKSPACE: 2MB (Weff) + 33.6MB (Xbf) + 256KB (partial) = ~36 MB.

typedef __attribute__((ext_vector_type(8))) short bf16x8;
typedef __attribute__((ext_vector_type(4))) float f32x4;

struct alignas(16) bfvec8 { __hip_bfloat16 h[8]; };

__device__ __forceinline__ bfvec8 pack8(float4 a, float4 b) {
    bfvec8 o;
    o.h[0] = __float2bfloat16(a.x); o.h[1] = __float2bfloat16(a.y);
    o.h[2] = __float2bfloat16(a.z); o.h[3] = __float2bfloat16(a.w);
    o.h[4] = __float2bfloat16(b.x); o.h[5] = __float2bfloat16(b.y);
    o.h[6] = __float2bfloat16(b.z); o.h[7] = __float2bfloat16(b.w);
    return o;
}

// ---------------- prep: weff (blocks 0..255) + X->bf16 cvt (blocks 256..2303) ----------
__global__ __launch_bounds__(256)
void prep(const float* __restrict__ Wo, const float* __restrict__ Wv,
          __hip_bfloat16* __restrict__ Weff,
          const float* __restrict__ X, __hip_bfloat16* __restrict__ Xbf) {
    __shared__ __align__(16) __hip_bfloat16 As[64 * 32];
    __shared__ __align__(16) __hip_bfloat16 Bs[64 * 32];
    __shared__ __align__(16) float Bf[32 * 65];

    const int tid = threadIdx.x;

    if (blockIdx.x >= 256) {
        // ---- X (16384x1024 fp32) -> Xbf bf16, vectorized grid-stride ----
        const size_t nv = (size_t)16384 * 1024 / 8;          // 2,097,152 vec8
        const size_t stride = (size_t)2048 * 256;
        for (size_t i = (size_t)(blockIdx.x - 256) * 256 + tid; i < nv; i += stride) {
            const float4 a = *(const float4*)(X + i * 8);
            const float4 b = *(const float4*)(X + i * 8 + 4);
            *(bfvec8*)(Xbf + i * 8) = pack8(a, b);
        }
        return;
    }

    // ---- weff body (validated): Weff = 0.125 * Wo @ Wv ----
    const int lane = tid & 63;
    const int wave = tid >> 6;
    const int wm   = wave >> 1;
    const int wn   = wave & 1;
    const int quad = lane >> 4;
    const int tr   = lane & 15;
    const int m0   = (blockIdx.x >> 4) * 64;
    const int n0   = (blockIdx.x & 15) * 64;

    f32x4 acc[2][2];
#pragma unroll
    for (int i = 0; i < 2; ++i)
#pragma unroll
        for (int j = 0; j < 2; ++j)
            acc[i][j] = (f32x4){0.f, 0.f, 0.f, 0.f};

    for (int kt = 0; kt < 512; kt += 32) {
        {
            int r = tid >> 2, c = tid & 3;
            int s = (r >> 1) & 3;
            int kg = (c ^ s) << 3;
            const float* sp = Wo + (size_t)(m0 + r) * 512 + kt + kg;
            float4 a = *(const float4*)sp, b = *(const float4*)(sp + 4);
            *(bfvec8*)(As + r * 32 + (c << 3)) = pack8(a, b);
        }
        {
            int kr = tid >> 3, c8 = (tid & 7) << 3;
            const float* sp = Wv + (size_t)(kt + kr) * 1024 + n0 + c8;
            float4 a = *(const float4*)sp, b = *(const float4*)(sp + 4);
            *(float4*)(Bf + kr * 65 + c8)     = a;
            *(float4*)(Bf + kr * 65 + c8 + 4) = b;
        }
        __syncthreads();
        {
            int n = tid >> 2, cc = tid & 3, k8 = cc << 3;
            float4 a, b;
            a.x = Bf[(k8 + 0) * 65 + n]; a.y = Bf[(k8 + 1) * 65 + n];
            a.z = Bf[(k8 + 2) * 65 + n]; a.w = Bf[(k8 + 3) * 65 + n];
            b.x = Bf[(k8 + 4) * 65 + n]; b.y = Bf[(k8 + 5) * 65 + n];
            b.z = Bf[(k8 + 6) * 65 + n]; b.w = Bf[(k8 + 7) * 65 + n];
            int cs = cc ^ ((n >> 1) & 3);
            *(bfvec8*)(Bs + n * 32 + cs * 8) = pack8(a, b);
        }
        __syncthreads();

        bf16x8 af[2], bfr[2];
#pragma unroll
        for (int mi = 0; mi < 2; ++mi) {
            int r = wm * 32 + mi * 16 + tr;
            int c = quad ^ ((r >> 1) & 3);
            af[mi] = *(const bf16x8*)(As + r * 32 + c * 8);
        }
#pragma unroll
        for (int ni = 0; ni < 2; ++ni) {
            int r = wn * 32 + ni * 16 + tr;
            int c = quad ^ ((r >> 1) & 3);
            bfr[ni] = *(const bf16x8*)(Bs + r * 32 + c * 8);
        }
#pragma unroll
        for (int mi = 0; mi < 2; ++mi)
#pragma unroll
            for (int ni = 0; ni < 2; ++ni)
                acc[mi][ni] = __builtin_amdgcn_mfma_f32_16x16x32_bf16(
                    af[mi], bfr[ni], acc[mi][ni], 0, 0, 0);
        __syncthreads();
    }

#pragma unroll
    for (int mi = 0; mi < 2; ++mi)
#pragma unroll
        for (int ni = 0; ni < 2; ++ni) {
            const int col = n0 + wn * 32 + ni * 16 + tr;
#pragma unroll
            for (int r = 0; r < 4; ++r) {
                const int row = m0 + wm * 32 + mi * 16 + quad * 4 + r;
                Weff[(size_t)row * 1024 + col] =
                    __float2bfloat16(acc[mi][ni][r] * 0.125f);
            }
        }
}

// ---------------- main_fused: y = Xbf @ Weff^T + b, then RMSNorm, cooperative ----------
// M=16384, N=1024, K=1024. Grid 256 blocks (64 m x 4 n), 512 threads (8 waves).
// LDS 128KB dbuf: buf b at b*32768 elems; A @ +0, B @ +16384; halves of 8192 elems.

#define GLL(gp, lp) __builtin_amdgcn_global_load_lds( \
    (const __attribute__((address_space(1))) void*)(gp), \
    (__attribute__((address_space(3))) void*)(lp), 16, 0, 0)

#define STAGE_A(BUF, H, U) do { \
    GLL(Xbf + Ab0 + (size_t)(H) * 131072 + (size_t)(U) * 64, \
        sm + (BUF) * 32768 + (H) * 8192 + ldsA);             \
    GLL(Xbf + Ab1 + (size_t)(H) * 131072 + (size_t)(U) * 64, \
        sm + (BUF) * 32768 + (H) * 8192 + 4096 + ldsA);      \
} while (0)

#define STAGE_B(BUF, H, U) do { \
    GLL(Bt + Bb0 + (size_t)(H) * 131072 + (size_t)(U) * 64,  \
        sm + (BUF) * 32768 + 16384 + (H) * 8192 + ldsA);     \
    GLL(Bt + Bb1 + (size_t)(H) * 131072 + (size_t)(U) * 64,  \
        sm + (BUF) * 32768 + 16384 + (H) * 8192 + 4096 + ldsA); \
} while (0)

__global__ __launch_bounds__(512, 2)
void main_fused(const __hip_bfloat16* __restrict__ Xbf,
                const __hip_bfloat16* __restrict__ Bt,
                const float* __restrict__ bias,
                const float* __restrict__ g,
                float* __restrict__ partial,
                float* __restrict__ out) {
    __shared__ __align__(16) __hip_bfloat16 sm[2 * 32768];   // 128 KiB
    __shared__ float wpart[8][256];                          // 8 KiB
    __shared__ float scs[256];                               // 1 KiB

    const int tid  = threadIdx.x;          // 0..511
    const int lane = tid & 63;
    const int wc   = tid >> 6;             // wave = col group 0..7 (cols wc*32)
    const int quad = lane >> 4;
    const int tr   = lane & 15;
    const int rlow = tr & 7;

    // XCD-aware: XCD x gets orig chunk [x*32, x*32+32) (8 m-strips x 4 n)
    const int xcd  = blockIdx.x & 7;
    const int orig = xcd * 32 + (blockIdx.x >> 3);
    const int m0   = (orig >> 2) * 256;
    const int n0   = (orig & 3) * 256;
    const int ntl  = orig & 3;

    // Staging constants. Slot s in {tid, tid+512}: r=s>>3, c=s&7, kg=((c^(r&7))<<3).
    const int r0 = tid >> 3,            c0 = tid & 7;
    const int r1 = (tid + 512) >> 3,    c1 = tid & 7;
    const size_t Ab0 = (size_t)(m0 + r0) * 1024 + ((c0 ^ (r0 & 7)) << 3);
    const size_t Ab1 = (size_t)(m0 + r1) * 1024 + ((c1 ^ (r1 & 7)) << 3);
    const size_t Bb0 = (size_t)(n0 + r0) * 1024 + ((c0 ^ (r0 & 7)) << 3);
    const size_t Bb1 = (size_t)(n0 + r1) * 1024 + ((c1 ^ (r1 & 7)) << 3);
    const int ldsA = tid * 8;

    int ac[2];
#pragma unroll
    for (int ko = 0; ko < 2; ++ko) ac[ko] = ((ko * 4 + quad) ^ rlow) * 8;
    const int rdA = tr * 64;
    const int rdB = wc * 2048 + tr * 64;

    f32x4 acc[16][2];
#pragma unroll
    for (int f = 0; f < 16; ++f)
#pragma unroll
        for (int ni = 0; ni < 2; ++ni)
            acc[f][ni] = (f32x4){0.f, 0.f, 0.f, 0.f};

    // ---- Prologue: stage [0.B0 0.B1 0.A0 0.A1 1.B0 1.B1 1.A0] = 14 loads ----
    STAGE_B(0, 0, 0); STAGE_B(0, 1, 0); STAGE_A(0, 0, 0); STAGE_A(0, 1, 0);
    STAGE_B(1, 0, 1); STAGE_B(1, 1, 1); STAGE_A(1, 0, 1);
    asm volatile("s_waitcnt vmcnt(6)" ::: "memory");
    __builtin_amdgcn_s_barrier();

    bf16x8 bfr[2][2];

    // ---- Main loop: 16 K-tiles, double-unrolled for static buffer bases ----
    for (int it = 0; it < 8; ++it) {
#pragma unroll
        for (int rb = 0; rb < 2; ++rb) {
            const int u = it * 2 + rb;
#pragma unroll
            for (int p = 0; p < 4; ++p) {
                bf16x8 af[4][2];
#pragma unroll
                for (int mi = 0; mi < 4; ++mi)
#pragma unroll
                    for (int ko = 0; ko < 2; ++ko)
                        af[mi][ko] = *(const bf16x8*)(
                            sm + rb * 32768 + p * 4096 + mi * 1024 + rdA + ac[ko]);
                if (p == 0) {
#pragma unroll
                    for (int ni = 0; ni < 2; ++ni)
#pragma unroll
                        for (int ko = 0; ko < 2; ++ko)
                            bfr[ni][ko] = *(const bf16x8*)(
                                sm + rb * 32768 + 16384 + rdB + ni * 1024 + ac[ko]);
                }

                if (p == 0)      { if (u + 1 < 16) STAGE_A(rb ^ 1, 1, u + 1); }
                else if (p == 1) { if (u + 2 < 16) STAGE_B(rb, 0, u + 2); }
                else if (p == 2) { if (u + 2 < 16) STAGE_B(rb, 1, u + 2); }
                else             { if (u + 2 < 16) STAGE_A(rb, 0, u + 2); }

                if (p == 0) asm volatile("s_waitcnt lgkmcnt(8)" ::: "memory");
                __builtin_amdgcn_s_barrier();
                asm volatile("s_waitcnt lgkmcnt(0)" ::: "memory");
                __builtin_amdgcn_sched_barrier(0);

                __builtin_amdgcn_s_setprio(1);
#pragma unroll
                for (int mi = 0; mi < 4; ++mi)
#pragma unroll
                    for (int ni = 0; ni < 2; ++ni)
#pragma unroll
                        for (int ko = 0; ko < 2; ++ko)
                            acc[p * 4 + mi][ni] = __builtin_amdgcn_mfma_f32_16x16x32_bf16(
                                af[mi][ko], bfr[ni][ko], acc[p * 4 + mi][ni], 0, 0, 0);
                __builtin_amdgcn_s_setprio(0);

                if (p == 3) {
                    if (u <= 13)      asm volatile("s_waitcnt vmcnt(6)" ::: "memory");
                    else if (u == 14) asm volatile("s_waitcnt vmcnt(0)" ::: "memory");
                    if (u < 15) __builtin_amdgcn_s_barrier();
                } else {
                    __builtin_amdgcn_s_barrier();
                }
            }
        }
    }

    // ---- Fused epilogue: bias + per-row sum-of-squares from registers ----
    float bv[2]; int col[2];
#pragma unroll
    for (int ni = 0; ni < 2; ++ni) {
        col[ni] = n0 + wc * 32 + ni * 16 + tr;
        bv[ni]  = bias[col[ni]];
    }
#pragma unroll
    for (int f = 0; f < 16; ++f)
#pragma unroll
        for (int rr = 0; rr < 4; ++rr) {
            float v = 0.f;
#pragma unroll
            for (int ni = 0; ni < 2; ++ni) {
                acc[f][ni][rr] += bv[ni];
                v += acc[f][ni][rr] * acc[f][ni][rr];
            }
            // reduce over the 16 tr-lanes of this quad (xor masks stay in-group)
#pragma unroll
            for (int msk = 1; msk < 16; msk <<= 1)
                v += __shfl_xor(v, msk, 64);
            if (tr == 0) wpart[wc][f * 16 + quad * 4 + rr] = v;
        }
    __syncthreads();
    if (tid < 256) {
        float s = 0.f;
#pragma unroll
        for (int w = 0; w < 8; ++w) s += wpart[w][tid];
        partial[(size_t)(m0 + tid) * 4 + ntl] = s;   // written exactly once
    }

    cg::this_grid().sync();                          // device-scope fence + barrier

    if (tid < 256) {
        const float* pr = partial + (size_t)(m0 + tid) * 4;
        const float s = pr[0] + pr[1] + pr[2] + pr[3];
        scs[tid] = 32.0f / fmaxf(sqrtf(s), 1e-12f);
    }
    __syncthreads();

    // ---- Write fp32 output straight from registers ----
    float gv[2];
#pragma unroll
    for (int ni = 0; ni < 2; ++ni) gv[ni] = g[col[ni]];
#pragma unroll
    for (int f = 0; f < 16; ++f)
#pragma unroll
        for (int rr = 0; rr < 4; ++rr) {
            const int rowin = f * 16 + quad * 4 + rr;
            const float sc = scs[rowin];
#pragma unroll
            for (int ni = 0; ni < 2; ++ni)
                out[(size_t)(m0 + rowin) * 1024 + col[ni]] =
                    acc[f][ni][rr] * sc * gv[ni];
        }
}

extern "C" void kernel_launch(void* const* d_in, const int* in_sizes, int n_in,
                              void* d_out, int out_size, void* d_ws, size_t ws_size,
                              hipStream_t stream) {
    const float* x     = (const float*)d_in[0];   // (16384, 1024)
    const float* w_qkv = (const float*)d_in[1];   // (1536, 1024)
    const float* w_out = (const float*)d_in[2];   // (1024, 512)
    const float* b_out = (const float*)d_in[3];   // (1024,)
    const float* g     = (const float*)d_in[4];   // (1, 1024)

    const int B = 16384, D = 1024, H = 512;
    const float* wv = w_qkv + (size_t)2 * H * D;  // v-rows: (512, 1024)

    char* ws = (char*)d_ws;
    size_t off = 0;
    __hip_bfloat16* weff_bf = (__hip_bfloat16*)(ws + off); off += (size_t)D * D * 2;   // 2 MB
    __hip_bfloat16* x_bf    = (__hip_bfloat16*)(ws + off); off += (size_t)B * D * 2;   // 33.6 MB
    float*          part    = (float*)(ws + off);          off += (size_t)B * 4 * 4;   // 256 KB

    prep<<<256 + 2048, 256, 0, stream>>>(w_out, wv, weff_bf, x, x_bf);

    {
        const __hip_bfloat16* a0 = x_bf;
        const __hip_bfloat16* a1 = weff_bf;
        const float* a2 = b_out;
        const float* a3 = g;
        float* a4 = part;
        float* a5 = (float*)d_out;
        void* args[] = {&a0, &a1, &a2, &a3, &a4, &a5};
        hipLaunchCooperativeKernel((void*)main_fused, dim3(256), dim3(512),
                                   args, 0, stream);
    }
}

// Round 4
// 209.611 us; speedup vs baseline: 1.0637x; 1.0637x over previous
//
#include <hip/hip_runtime.h>
#include <hip/hip_bf16.h>

// LinearAttention_MLP on MI355X — round 9: round-7 structure, A read fp32 directly
// (T14 reg-staged cvt in the 8-phase schedule) -> Xbf intermediate ELIMINATED.
// Math: k-softmax over size-1 axis == 1 -> s = 0.125 exactly -> out = 0.125*v.
// Fold: y = x @ Weff^T, Weff = 0.125*Wo@Wv (1024x1024).
// Pipeline (3 launches):
//   weff_only  : Weff = bf16(0.125*Wo@Wv), 256 blocks (validated round-5 body)
//   main_gemm  : y_bf = bf16(X@Weff^T + b). 256x256 tile, BK=64, 512 thr, dbuf
//                128KB LDS. B via global_load_lds (counted vmcnt); A via
//                global fp32 -> regs (issued at p3, one tile ahead) -> pack8 ->
//                ds_write at next p3. vmcnt ledger (issue order pinned):
//                  p1: gll B(u+2)h0(2)   p2: gll B(u+2)h1(2)
//                  p3: vmcnt(4) [A(u+1) regs ready; B(u+1) older => also done]
//                      ds_write A(u+1) -> other buf; issue A(u+2) loads (8);
//                      barrier; lgkmcnt(0); MFMA; boundary barrier (bare).
//                  tails: u=14 vmcnt(0); u=15 compute-only.
//   rmsnorm2   : out = y/max(||y||,eps)*g*32  (fp32, unchanged)
//
// Swizzle convention (validated, 0 bank conflicts):
//   STORE: LDS chunk c holds GLOBAL chunk c ^ (r&7)  (swizzle the global k only)
//   READ : global chunk q lives in LDS chunk q ^ (r&7)
//
// WORKSPACE: 2MB (Weff) + 33.6MB (y_bf) = ~36 MB.

typedef __attribute__((ext_vector_type(8))) short bf16x8;
typedef __attribute__((ext_vector_type(4))) float f32x4;

struct alignas(16) bfvec8 { __hip_bfloat16 h[8]; };

__device__ __forceinline__ bfvec8 pack8(float4 a, float4 b) {
    bfvec8 o;
    o.h[0] = __float2bfloat16(a.x); o.h[1] = __float2bfloat16(a.y);
    o.h[2] = __float2bfloat16(a.z); o.h[3] = __float2bfloat16(a.w);
    o.h[4] = __float2bfloat16(b.x); o.h[5] = __float2bfloat16(b.y);
    o.h[6] = __float2bfloat16(b.z); o.h[7] = __float2bfloat16(b.w);
    return o;
}

// ---------------- weff_only: Weff = 0.125 * Wo @ Wv, fp32 in, bf16 out ----------------
__global__ __launch_bounds__(256)
void weff_only(const float* __restrict__ Wo, const float* __restrict__ Wv,
               __hip_bfloat16* __restrict__ Weff) {
    __shared__ __align__(16) __hip_bfloat16 As[64 * 32];
    __shared__ __align__(16) __hip_bfloat16 Bs[64 * 32];
    __shared__ __align__(16) float Bf[32 * 65];

    const int tid  = threadIdx.x;
    const int lane = tid & 63;
    const int wave = tid >> 6;
    const int wm   = wave >> 1;
    const int wn   = wave & 1;
    const int quad = lane >> 4;
    const int tr   = lane & 15;
    const int m0   = (blockIdx.x >> 4) * 64;
    const int n0   = (blockIdx.x & 15) * 64;

    f32x4 acc[2][2];
#pragma unroll
    for (int i = 0; i < 2; ++i)
#pragma unroll
        for (int j = 0; j < 2; ++j)
            acc[i][j] = (f32x4){0.f, 0.f, 0.f, 0.f};

    for (int kt = 0; kt < 512; kt += 32) {
        {
            int r = tid >> 2, c = tid & 3;
            int s = (r >> 1) & 3;
            int kg = (c ^ s) << 3;
            const float* sp = Wo + (size_t)(m0 + r) * 512 + kt + kg;
            float4 a = *(const float4*)sp, b = *(const float4*)(sp + 4);
            *(bfvec8*)(As + r * 32 + (c << 3)) = pack8(a, b);
        }
        {
            int kr = tid >> 3, c8 = (tid & 7) << 3;
            const float* sp = Wv + (size_t)(kt + kr) * 1024 + n0 + c8;
            float4 a = *(const float4*)sp, b = *(const float4*)(sp + 4);
            *(float4*)(Bf + kr * 65 + c8)     = a;
            *(float4*)(Bf + kr * 65 + c8 + 4) = b;
        }
        __syncthreads();
        {
            int n = tid >> 2, cc = tid & 3, k8 = cc << 3;
            float4 a, b;
            a.x = Bf[(k8 + 0) * 65 + n]; a.y = Bf[(k8 + 1) * 65 + n];
            a.z = Bf[(k8 + 2) * 65 + n]; a.w = Bf[(k8 + 3) * 65 + n];
            b.x = Bf[(k8 + 4) * 65 + n]; b.y = Bf[(k8 + 5) * 65 + n];
            b.z = Bf[(k8 + 6) * 65 + n]; b.w = Bf[(k8 + 7) * 65 + n];
            int cs = cc ^ ((n >> 1) & 3);
            *(bfvec8*)(Bs + n * 32 + cs * 8) = pack8(a, b);
        }
        __syncthreads();

        bf16x8 af[2], bfr[2];
#pragma unroll
        for (int mi = 0; mi < 2; ++mi) {
            int r = wm * 32 + mi * 16 + tr;
            int c = quad ^ ((r >> 1) & 3);
            af[mi] = *(const bf16x8*)(As + r * 32 + c * 8);
        }
#pragma unroll
        for (int ni = 0; ni < 2; ++ni) {
            int r = wn * 32 + ni * 16 + tr;
            int c = quad ^ ((r >> 1) & 3);
            bfr[ni] = *(const bf16x8*)(Bs + r * 32 + c * 8);
        }
#pragma unroll
        for (int mi = 0; mi < 2; ++mi)
#pragma unroll
            for (int ni = 0; ni < 2; ++ni)
                acc[mi][ni] = __builtin_amdgcn_mfma_f32_16x16x32_bf16(
                    af[mi], bfr[ni], acc[mi][ni], 0, 0, 0);
        __syncthreads();
    }

#pragma unroll
    for (int mi = 0; mi < 2; ++mi)
#pragma unroll
        for (int ni = 0; ni < 2; ++ni) {
            const int col = n0 + wn * 32 + ni * 16 + tr;
#pragma unroll
            for (int r = 0; r < 4; ++r) {
                const int row = m0 + wm * 32 + mi * 16 + quad * 4 + r;
                Weff[(size_t)row * 1024 + col] =
                    __float2bfloat16(acc[mi][ni][r] * 0.125f);
            }
        }
}

// ---------------- main GEMM: y = X @ Weff^T + b (A fp32, cvt fused) ----------------
// M=16384, N=1024, K=1024. Grid 256 blocks (64 m x 4 n), 512 threads (8 waves).
// LDS 128KB: buf b at b*32768 elems; A @ +0 (256x64), B @ +16384 (256x64).

#define GLL(gp, lp) __builtin_amdgcn_global_load_lds( \
    (const __attribute__((address_space(1))) void*)(gp), \
    (__attribute__((address_space(3))) void*)(lp), 16, 0, 0)

#define STAGE_B(BUF, H, U) do { \
    GLL(Bt + Bb0 + (size_t)(H) * 131072 + (size_t)(U) * 64,  \
        sm + (BUF) * 32768 + 16384 + (H) * 8192 + tid * 8);  \
    GLL(Bt + Bb1 + (size_t)(H) * 131072 + (size_t)(U) * 64,  \
        sm + (BUF) * 32768 + 16384 + (H) * 8192 + 4096 + tid * 8); \
} while (0)

#define LOAD_A(U) do { \
    _Pragma("unroll") \
    for (int j = 0; j < 4; ++j) { \
        const float* s_ = Xrow + (size_t)(U) * 64 + aoff[j]; \
        pa[2*j]   = *(const float4*)s_; \
        pa[2*j+1] = *(const float4*)(s_ + 4); \
    } \
} while (0)

#define WRITE_A(BUF) do { \
    _Pragma("unroll") \
    for (int j = 0; j < 4; ++j) \
        *(bfvec8*)(sm + (BUF) * 32768 + tid * 32 + j * 8) = \
            pack8(pa[2*j], pa[2*j+1]); \
} while (0)

__global__ __launch_bounds__(512, 2)
void main_gemm(const float* __restrict__ X,
               const __hip_bfloat16* __restrict__ Bt,
               const float* __restrict__ bias,
               __hip_bfloat16* __restrict__ Y) {
    __shared__ __align__(16) __hip_bfloat16 sm[2 * 32768];   // 128 KiB

    const int tid  = threadIdx.x;          // 0..511
    const int lane = tid & 63;
    const int wc   = tid >> 6;             // wave = col group 0..7
    const int quad = lane >> 4;
    const int tr   = lane & 15;
    const int rlow = tr & 7;

    // XCD-aware: XCD x gets orig chunk [x*32, x*32+32) (8 m-strips x 4 n)
    const int xcd  = blockIdx.x & 7;
    const int orig = xcd * 32 + (blockIdx.x >> 3);
    const int m0   = (orig >> 2) * 256;
    const int n0   = (orig & 3) * 256;

    // B staging (global_load_lds, linear dest, inverse-swizzled global k).
    const int r0 = tid >> 3,         c0 = tid & 7;
    const int r1 = (tid + 512) >> 3, c1 = tid & 7;
    const size_t Bb0 = (size_t)(n0 + r0) * 1024 + ((c0 ^ (r0 & 7)) << 3);
    const size_t Bb1 = (size_t)(n0 + r1) * 1024 + ((c1 ^ (r1 & 7)) << 3);

    // A staging (fp32 -> regs -> pack8 -> ds_write). Thread owns row R = tid>>1,
    // chunks c = (tid&1)*4 + j. LDS elem (R*8+c)*8 = tid*32 + j*8 (linear).
    const int  Ra   = tid >> 1;
    const float* Xrow = X + (size_t)(m0 + Ra) * 1024;
    int aoff[4];
#pragma unroll
    for (int j = 0; j < 4; ++j)
        aoff[j] = ((((tid & 1) * 4 + j) ^ (Ra & 7)) << 3);

    // Read chunk offsets per ko: global chunk q = ko*4+quad lives in LDS chunk q^rlow.
    int ac[2];
#pragma unroll
    for (int ko = 0; ko < 2; ++ko) ac[ko] = ((ko * 4 + quad) ^ rlow) * 8;
    const int rdA = tr * 64;                 // + p*4096 + mi*1024
    const int rdB = wc * 2048 + tr * 64;     // + ni*1024

    f32x4 acc[16][2];
#pragma unroll
    for (int f = 0; f < 16; ++f)
#pragma unroll
        for (int ni = 0; ni < 2; ++ni)
            acc[f][ni] = (f32x4){0.f, 0.f, 0.f, 0.f};

    float4 pa[8];

    // ---- Prologue ----
    LOAD_A(0);                                            // 8 loads (oldest)
    __builtin_amdgcn_sched_barrier(0);
    STAGE_B(0, 0, 0); STAGE_B(0, 1, 0);                   // 4 glls
    STAGE_B(1, 0, 1); STAGE_B(1, 1, 1);                   // 4 glls
    __builtin_amdgcn_sched_barrier(0);
    asm volatile("s_waitcnt vmcnt(8)" ::: "memory");      // A(0) done, B flying
    WRITE_A(0);
    __builtin_amdgcn_sched_barrier(0);
    LOAD_A(1);                                            // 8 loads (newest)
    __builtin_amdgcn_sched_barrier(0);
    asm volatile("s_waitcnt vmcnt(8) lgkmcnt(0)" ::: "memory"); // B(0),B(1) done
    __builtin_amdgcn_s_barrier();

    bf16x8 bfr[2][2];

    // ---- Main loop: 16 K-tiles, double-unrolled for static buffer bases ----
    for (int it = 0; it < 8; ++it) {
#pragma unroll
        for (int rb = 0; rb < 2; ++rb) {
            const int u = it * 2 + rb;
#pragma unroll
            for (int p = 0; p < 4; ++p) {
                bf16x8 af[4][2];
#pragma unroll
                for (int mi = 0; mi < 4; ++mi)
#pragma unroll
                    for (int ko = 0; ko < 2; ++ko)
                        af[mi][ko] = *(const bf16x8*)(
                            sm + rb * 32768 + p * 4096 + mi * 1024 + rdA + ac[ko]);
                if (p == 0) {
#pragma unroll
                    for (int ni = 0; ni < 2; ++ni)
#pragma unroll
                        for (int ko = 0; ko < 2; ++ko)
                            bfr[ni][ko] = *(const bf16x8*)(
                                sm + rb * 32768 + 16384 + rdB + ni * 1024 + ac[ko]);
                }

                // staging per phase
                if (p == 1)      { if (u <= 13) STAGE_B(rb, 0, u + 2); }
                else if (p == 2) { if (u <= 13) STAGE_B(rb, 1, u + 2); }
                else if (p == 3) {
                    if (u <= 14) {
                        if (u <= 13) asm volatile("s_waitcnt vmcnt(4)" ::: "memory");
                        else         asm volatile("s_waitcnt vmcnt(0)" ::: "memory");
                        __builtin_amdgcn_sched_barrier(0);
                        WRITE_A(rb ^ 1);                  // A(u+1) -> other buffer
                        __builtin_amdgcn_sched_barrier(0);
                        if (u <= 13) LOAD_A(u + 2);       // 8 loads, newest
                        __builtin_amdgcn_sched_barrier(0);
                    }
                }

                if (p == 0) asm volatile("s_waitcnt lgkmcnt(8)" ::: "memory");
                __builtin_amdgcn_s_barrier();
                asm volatile("s_waitcnt lgkmcnt(0)" ::: "memory");
                __builtin_amdgcn_sched_barrier(0);

                __builtin_amdgcn_s_setprio(1);
#pragma unroll
                for (int mi = 0; mi < 4; ++mi)
#pragma unroll
                    for (int ni = 0; ni < 2; ++ni)
#pragma unroll
                        for (int ko = 0; ko < 2; ++ko)
                            acc[p * 4 + mi][ni] = __builtin_amdgcn_mfma_f32_16x16x32_bf16(
                                af[mi][ko], bfr[ni][ko], acc[p * 4 + mi][ni], 0, 0, 0);
                __builtin_amdgcn_s_setprio(0);

                if (p == 3) {
                    if (u < 15) __builtin_amdgcn_s_barrier();   // boundary (hazards retired)
                } else {
                    __builtin_amdgcn_s_barrier();
                }
            }
        }
    }

    // ---- Epilogue: C/D layout col = lane&15, row = quad*4 + reg ----
    float bv[2]; int col[2];
#pragma unroll
    for (int ni = 0; ni < 2; ++ni) {
        col[ni] = n0 + wc * 32 + ni * 16 + tr;
        bv[ni]  = bias[col[ni]];
    }
#pragma unroll
    for (int f = 0; f < 16; ++f)
#pragma unroll
        for (int ni = 0; ni < 2; ++ni)
#pragma unroll
            for (int rr = 0; rr < 4; ++rr) {
                const int row = m0 + f * 16 + quad * 4 + rr;
                Y[(size_t)row * 1024 + col[ni]] =
                    __float2bfloat16(acc[f][ni][rr] + bv[ni]);
            }
}

// ---------------- norm: out = y / max(||y||,eps) * g * 32, 2 rows/block ----------------
__global__ __launch_bounds__(256)
void rmsnorm2(const __hip_bfloat16* __restrict__ y, const float* __restrict__ g,
              float* __restrict__ out) {
    const int wave = threadIdx.x >> 6;
    const int sub  = wave >> 1;
    const int t    = threadIdx.x & 127;
    const int row  = blockIdx.x * 2 + sub;
    const size_t base = (size_t)row * 1024 + t * 8;

    union { uint4 u; ushort s[8]; } U;
    U.u = *(const uint4*)(y + base);
    float v[8];
#pragma unroll
    for (int j = 0; j < 8; ++j)
        v[j] = __bfloat162float(*(const __hip_bfloat16*)&U.s[j]);

    float ss = 0.f;
#pragma unroll
    for (int j = 0; j < 8; ++j) ss += v[j] * v[j];
#pragma unroll
    for (int off = 32; off > 0; off >>= 1)
        ss += __shfl_down(ss, off, 64);

    __shared__ float wsum[4];
    if ((threadIdx.x & 63) == 0) wsum[wave] = ss;
    __syncthreads();
    const float total = wsum[sub * 2] + wsum[sub * 2 + 1];
    const float sc = 32.0f / fmaxf(sqrtf(total), 1e-12f);

    const float4 g0 = *(const float4*)(g + t * 8);
    const float4 g1 = *(const float4*)(g + t * 8 + 4);
    float4 o0, o1;
    o0.x = v[0] * sc * g0.x; o0.y = v[1] * sc * g0.y;
    o0.z = v[2] * sc * g0.z; o0.w = v[3] * sc * g0.w;
    o1.x = v[4] * sc * g1.x; o1.y = v[5] * sc * g1.y;
    o1.z = v[6] * sc * g1.z; o1.w = v[7] * sc * g1.w;
    *(float4*)(out + base)     = o0;
    *(float4*)(out + base + 4) = o1;
}

extern "C" void kernel_launch(void* const* d_in, const int* in_sizes, int n_in,
                              void* d_out, int out_size, void* d_ws, size_t ws_size,
                              hipStream_t stream) {
    const float* x     = (const float*)d_in[0];   // (16384, 1024)
    const float* w_qkv = (const float*)d_in[1];   // (1536, 1024)
    const float* w_out = (const float*)d_in[2];   // (1024, 512)
    const float* b_out = (const float*)d_in[3];   // (1024,)
    const float* g     = (const float*)d_in[4];   // (1, 1024)

    const int B = 16384, D = 1024, H = 512;
    const float* wv = w_qkv + (size_t)2 * H * D;  // v-rows: (512, 1024)

    char* ws = (char*)d_ws;
    size_t off = 0;
    __hip_bfloat16* weff_bf = (__hip_bfloat16*)(ws + off); off += (size_t)D * D * 2;  // 2 MB
    __hip_bfloat16* y_bf    = (__hip_bfloat16*)(ws + off); off += (size_t)B * D * 2;  // 33.6 MB

    weff_only<<<256, 256, 0, stream>>>(w_out, wv, weff_bf);
    main_gemm<<<256, 512, 0, stream>>>(x, weff_bf, b_out, y_bf);
    rmsnorm2<<<B / 2, 256, 0, stream>>>(y_bf, g, (float*)d_out);
}

// Round 5
// 179.559 us; speedup vs baseline: 1.2417x; 1.1674x over previous
//
#include <hip/hip_runtime.h>
#include <hip/hip_bf16.h>

// LinearAttention_MLP on MI355X — round 10: full-row blocks + fused RMSNorm epilogue.
// Math: k-softmax over size-1 axis == 1 -> s = 0.125 exactly -> out = 0.125*v.
// Fold: y = x @ Weff^T, Weff = 0.125*Wo@Wv (1024x1024).
// Pipeline (2 launches):
//   weff_only  : Weff = bf16(0.125*Wo@Wv), 256 blocks (validated round-5 body)
//   main_fused : block = 64 rows x ALL 1024 cols, 256 blocks (1/CU), 512 thr
//                (8 waves x 64x128). BK=32, 32 K-tiles. B = whole Weff, staged
//                per-tile via global_load_lds (L2-resident: 2MB < 4MB/XCD).
//                A = X fp32 -> reg -> pack4 -> ds_write_b64 (linear, conflict-
//                free). Staging writes ONLY the other buffer -> ONE barrier per
//                tile. vmcnt ledger: [4 gll B][1 A-load][4 gll B]; vmcnt(4)
//                before A ds_write (after MFMA), vmcnt(0)+lgkmcnt(0) at boundary.
//                Epilogue: bias -> per-row sumsq (shfl-xor + LDS cross-wave) ->
//                sc = 32/max(||y||,eps) -> out fp32 from registers. No y_bf,
//                no Xbf, no rmsnorm kernel, no grid.sync.
//
// Swizzle (round-3/5 validated convention, BK=32 -> 4 chunks, mask 3):
//   STORE: LDS chunk c of row r holds GLOBAL chunk c ^ (r&3)
//   READ : global chunk q of row r lives in LDS chunk q ^ (r&3)
//
// WORKSPACE: 2 MB (Weff) only.

typedef __attribute__((ext_vector_type(8))) short bf16x8;
typedef __attribute__((ext_vector_type(4))) float f32x4;

struct alignas(16) bfvec8 { __hip_bfloat16 h[8]; };
struct alignas(8)  bfvec4 { __hip_bfloat16 h[4]; };

__device__ __forceinline__ bfvec8 pack8(float4 a, float4 b) {
    bfvec8 o;
    o.h[0] = __float2bfloat16(a.x); o.h[1] = __float2bfloat16(a.y);
    o.h[2] = __float2bfloat16(a.z); o.h[3] = __float2bfloat16(a.w);
    o.h[4] = __float2bfloat16(b.x); o.h[5] = __float2bfloat16(b.y);
    o.h[6] = __float2bfloat16(b.z); o.h[7] = __float2bfloat16(b.w);
    return o;
}

__device__ __forceinline__ bfvec4 pack4(float4 a) {
    bfvec4 o;
    o.h[0] = __float2bfloat16(a.x); o.h[1] = __float2bfloat16(a.y);
    o.h[2] = __float2bfloat16(a.z); o.h[3] = __float2bfloat16(a.w);
    return o;
}

// ---------------- weff_only: Weff = 0.125 * Wo @ Wv, fp32 in, bf16 out ----------------
__global__ __launch_bounds__(256)
void weff_only(const float* __restrict__ Wo, const float* __restrict__ Wv,
               __hip_bfloat16* __restrict__ Weff) {
    __shared__ __align__(16) __hip_bfloat16 As[64 * 32];
    __shared__ __align__(16) __hip_bfloat16 Bs[64 * 32];
    __shared__ __align__(16) float Bf[32 * 65];

    const int tid  = threadIdx.x;
    const int lane = tid & 63;
    const int wave = tid >> 6;
    const int wm   = wave >> 1;
    const int wn   = wave & 1;
    const int quad = lane >> 4;
    const int tr   = lane & 15;
    const int m0   = (blockIdx.x >> 4) * 64;
    const int n0   = (blockIdx.x & 15) * 64;

    f32x4 acc[2][2];
#pragma unroll
    for (int i = 0; i < 2; ++i)
#pragma unroll
        for (int j = 0; j < 2; ++j)
            acc[i][j] = (f32x4){0.f, 0.f, 0.f, 0.f};

    for (int kt = 0; kt < 512; kt += 32) {
        {
            int r = tid >> 2, c = tid & 3;
            int s = (r >> 1) & 3;
            int kg = (c ^ s) << 3;
            const float* sp = Wo + (size_t)(m0 + r) * 512 + kt + kg;
            float4 a = *(const float4*)sp, b = *(const float4*)(sp + 4);
            *(bfvec8*)(As + r * 32 + (c << 3)) = pack8(a, b);
        }
        {
            int kr = tid >> 3, c8 = (tid & 7) << 3;
            const float* sp = Wv + (size_t)(kt + kr) * 1024 + n0 + c8;
            float4 a = *(const float4*)sp, b = *(const float4*)(sp + 4);
            *(float4*)(Bf + kr * 65 + c8)     = a;
            *(float4*)(Bf + kr * 65 + c8 + 4) = b;
        }
        __syncthreads();
        {
            int n = tid >> 2, cc = tid & 3, k8 = cc << 3;
            float4 a, b;
            a.x = Bf[(k8 + 0) * 65 + n]; a.y = Bf[(k8 + 1) * 65 + n];
            a.z = Bf[(k8 + 2) * 65 + n]; a.w = Bf[(k8 + 3) * 65 + n];
            b.x = Bf[(k8 + 4) * 65 + n]; b.y = Bf[(k8 + 5) * 65 + n];
            b.z = Bf[(k8 + 6) * 65 + n]; b.w = Bf[(k8 + 7) * 65 + n];
            int cs = cc ^ ((n >> 1) & 3);
            *(bfvec8*)(Bs + n * 32 + cs * 8) = pack8(a, b);
        }
        __syncthreads();

        bf16x8 af[2], bfr[2];
#pragma unroll
        for (int mi = 0; mi < 2; ++mi) {
            int r = wm * 32 + mi * 16 + tr;
            int c = quad ^ ((r >> 1) & 3);
            af[mi] = *(const bf16x8*)(As + r * 32 + c * 8);
        }
#pragma unroll
        for (int ni = 0; ni < 2; ++ni) {
            int r = wn * 32 + ni * 16 + tr;
            int c = quad ^ ((r >> 1) & 3);
            bfr[ni] = *(const bf16x8*)(Bs + r * 32 + c * 8);
        }
#pragma unroll
        for (int mi = 0; mi < 2; ++mi)
#pragma unroll
            for (int ni = 0; ni < 2; ++ni)
                acc[mi][ni] = __builtin_amdgcn_mfma_f32_16x16x32_bf16(
                    af[mi], bfr[ni], acc[mi][ni], 0, 0, 0);
        __syncthreads();
    }

#pragma unroll
    for (int mi = 0; mi < 2; ++mi)
#pragma unroll
        for (int ni = 0; ni < 2; ++ni) {
            const int col = n0 + wn * 32 + ni * 16 + tr;
#pragma unroll
            for (int r = 0; r < 4; ++r) {
                const int row = m0 + wm * 32 + mi * 16 + quad * 4 + r;
                Weff[(size_t)row * 1024 + col] =
                    __float2bfloat16(acc[mi][ni][r] * 0.125f);
            }
        }
}

// ---------------- main_fused: y = X @ Weff^T + b, RMSNorm fused, fp32 out ----------------
// Block: 64 rows x 1024 cols. 256 blocks, 512 threads (8 waves, wave wc = cols
// wc*128..wc*128+127). BK=32, 32 K-tiles. LDS (bf16 elems):
//   A buf b:   b*2048      .. +2048   (64 x 32)
//   B buf b:   4096 + b*32768 .. +32768  (1024 x 32)

#define GLL(gp, lp) __builtin_amdgcn_global_load_lds( \
    (const __attribute__((address_space(1))) void*)(gp), \
    (__attribute__((address_space(3))) void*)(lp), 16, 0, 0)

__global__ __launch_bounds__(512, 2)
void main_fused(const float* __restrict__ X,
                const __hip_bfloat16* __restrict__ W,
                const float* __restrict__ bias,
                const float* __restrict__ g,
                float* __restrict__ out) {
    __shared__ __align__(16) __hip_bfloat16 sm[69632];   // 136 KiB
    __shared__ float wpart[8][64];
    __shared__ float scrow[64];

    const int tid  = threadIdx.x;          // 0..511
    const int lane = tid & 63;
    const int wc   = tid >> 6;             // wave = col group (128 cols)
    const int quad = lane >> 4;
    const int tr   = lane & 15;

    const int m0 = blockIdx.x * 64;

    // A staging: thread -> (row ra, half-chunk q). LDS elem tid*4 (8B, linear).
    const int ra = tid >> 3, q = tid & 7;
    const int aq = (((q >> 1) ^ (ra & 3)) << 3) + (q & 1) * 4;   // swizzled k-offset
    const float* Ag = X + (size_t)(m0 + ra) * 1024 + aq;
    const int AdsW = tid * 4;              // elems

    // B staging: 8 slots/thread, slot i -> row i*128 + (tid>>2), chunk tid&3.
    const int brow = tid >> 2;             // 0..127
    const int kswz = (((tid & 3) ^ (brow & 3)) << 3);

    // Frag read chunk: global chunk quad of row r lives in LDS chunk quad^(r&3),
    // and r&3 == tr&3 for every fragment row (A and B alike).
    const int ac = ((quad ^ (tr & 3)) << 3);

    f32x4 acc[4][8];
#pragma unroll
    for (int mi = 0; mi < 4; ++mi)
#pragma unroll
        for (int ni = 0; ni < 8; ++ni)
            acc[mi][ni] = (f32x4){0.f, 0.f, 0.f, 0.f};

    // ---- Prologue: stage tile 0 into buf 0 ----
    {
#pragma unroll
        for (int i = 0; i < 4; ++i)
            GLL(W + (size_t)(i * 128 + brow) * 1024 + kswz,
                sm + 4096 + (i * 512 + tid) * 8);
        float4 pav = *(const float4*)Ag;
#pragma unroll
        for (int i = 4; i < 8; ++i)
            GLL(W + (size_t)(i * 128 + brow) * 1024 + kswz,
                sm + 4096 + (i * 512 + tid) * 8);
        asm volatile("s_waitcnt vmcnt(4)" ::: "memory");
        *(bfvec4*)(sm + AdsW) = pack4(pav);
        asm volatile("s_waitcnt vmcnt(0) lgkmcnt(0)" ::: "memory");
        __builtin_amdgcn_s_barrier();
    }

    // ---- Main loop: 32 K-tiles, one barrier per tile, stage next into buf^1 ----
#define TILE(U, RB) do { \
    const int u_ = (U); \
    float4 pav; \
    if (u_ < 31) { \
        const int kt_ = (u_ + 1) * 32; \
        _Pragma("unroll") \
        for (int i = 0; i < 4; ++i) \
            GLL(W + (size_t)(i * 128 + brow) * 1024 + kt_ + kswz, \
                sm + 4096 + ((RB) ^ 1) * 32768 + (i * 512 + tid) * 8); \
        pav = *(const float4*)(Ag + kt_); \
        _Pragma("unroll") \
        for (int i = 4; i < 8; ++i) \
            GLL(W + (size_t)(i * 128 + brow) * 1024 + kt_ + kswz, \
                sm + 4096 + ((RB) ^ 1) * 32768 + (i * 512 + tid) * 8); \
    } \
    bf16x8 af[4], bfr[8]; \
    _Pragma("unroll") \
    for (int mi = 0; mi < 4; ++mi) \
        af[mi] = *(const bf16x8*)(sm + (RB) * 2048 + (mi * 16 + tr) * 32 + ac); \
    _Pragma("unroll") \
    for (int ni = 0; ni < 8; ++ni) \
        bfr[ni] = *(const bf16x8*)(sm + 4096 + (RB) * 32768 + \
                                   (wc * 128 + ni * 16 + tr) * 32 + ac); \
    asm volatile("s_waitcnt lgkmcnt(0)" ::: "memory"); \
    __builtin_amdgcn_sched_barrier(0); \
    __builtin_amdgcn_s_setprio(1); \
    _Pragma("unroll") \
    for (int mi = 0; mi < 4; ++mi) \
        _Pragma("unroll") \
        for (int ni = 0; ni < 8; ++ni) \
            acc[mi][ni] = __builtin_amdgcn_mfma_f32_16x16x32_bf16( \
                af[mi], bfr[ni], acc[mi][ni], 0, 0, 0); \
    __builtin_amdgcn_s_setprio(0); \
    if (u_ < 31) { \
        asm volatile("s_waitcnt vmcnt(4)" ::: "memory"); \
        *(bfvec4*)(sm + ((RB) ^ 1) * 2048 + AdsW) = pack4(pav); \
    } \
    asm volatile("s_waitcnt vmcnt(0) lgkmcnt(0)" ::: "memory"); \
    __builtin_amdgcn_s_barrier(); \
} while (0)

    for (int it = 0; it < 16; ++it) {
        TILE(it * 2,     0);
        TILE(it * 2 + 1, 1);
    }
#undef TILE

    // ---- Fused epilogue: bias -> per-row ||y||^2 -> sc -> fp32 out ----
    float bvv[8], gvv[8];
    int coln[8];
#pragma unroll
    for (int ni = 0; ni < 8; ++ni) {
        coln[ni] = wc * 128 + ni * 16 + tr;
        bvv[ni] = bias[coln[ni]];
        gvv[ni] = g[coln[ni]];
    }

#pragma unroll
    for (int mi = 0; mi < 4; ++mi)
#pragma unroll
        for (int rr = 0; rr < 4; ++rr) {
            float p = 0.f;
#pragma unroll
            for (int ni = 0; ni < 8; ++ni) {
                const float t = acc[mi][ni][rr] + bvv[ni];
                acc[mi][ni][rr] = t;
                p += t * t;
            }
            // reduce over the 16 tr-lanes (same row, 128 cols of this wave)
#pragma unroll
            for (int msk = 1; msk < 16; msk <<= 1)
                p += __shfl_xor(p, msk, 64);
            if (tr == 0) wpart[wc][mi * 16 + quad * 4 + rr] = p;
        }
    __syncthreads();

    if (tid < 64) {
        float s = 0.f;
#pragma unroll
        for (int w = 0; w < 8; ++w) s += wpart[w][tid];
        scrow[tid] = 32.0f / fmaxf(sqrtf(s), 1e-12f);
    }
    __syncthreads();

#pragma unroll
    for (int mi = 0; mi < 4; ++mi)
#pragma unroll
        for (int rr = 0; rr < 4; ++rr) {
            const int r16 = mi * 16 + quad * 4 + rr;
            const float sc = scrow[r16];
#pragma unroll
            for (int ni = 0; ni < 8; ++ni)
                out[(size_t)(m0 + r16) * 1024 + coln[ni]] =
                    acc[mi][ni][rr] * sc * gvv[ni];
        }
}

extern "C" void kernel_launch(void* const* d_in, const int* in_sizes, int n_in,
                              void* d_out, int out_size, void* d_ws, size_t ws_size,
                              hipStream_t stream) {
    const float* x     = (const float*)d_in[0];   // (16384, 1024)
    const float* w_qkv = (const float*)d_in[1];   // (1536, 1024)
    const float* w_out = (const float*)d_in[2];   // (1024, 512)
    const float* b_out = (const float*)d_in[3];   // (1024,)
    const float* g     = (const float*)d_in[4];   // (1, 1024)

    const int D = 1024, H = 512;
    const float* wv = w_qkv + (size_t)2 * H * D;  // v-rows: (512, 1024)

    __hip_bfloat16* weff_bf = (__hip_bfloat16*)d_ws;   // 2 MB

    weff_only<<<256, 256, 0, stream>>>(w_out, wv, weff_bf);
    main_fused<<<256, 512, 0, stream>>>(x, weff_bf, b_out, g, (float*)d_out);
}